// Round 10
// baseline (296.416 us; speedup 1.0000x reference)
//
#include <hip/hip_runtime.h>

#define N_NODES_C 1000
#define N_EDGES_C 8000
#define BATCH_C   64
#define IN_DIM_C  64
#define HID_C     128
#define NT (BATCH_C * N_NODES_C)   // 64000 total nodes
#define ET (BATCH_C * N_EDGES_C)   // 512000 total edges

// workspace layout (float offsets)
#define WS_DEG    0                 // 64000 f: dinv (written by csr_scan)
#define WS_EWS    64000             // 8000 f: ews; dead after scatter ->
#define WS_G2048  64000             //   g2048 (2048 f) lives here afterwards
#define WS_PCK    72000             // 64000 u64: packed cnt<<32|deg -> cursors
#define WS_ROWP   200000            // 64*1024 i: per-graph CSR row starts
#define WS_PEDGE  265536            // 512000 int2: (src_global, norm) CSR order
#define WS_PART2  72000             // small-ws path partials (dead CSR region)
#define WS_H2     1813824           // 8192000 f: h2 (dead after spmm ->
                                    //   big-path reduce_g partials)
#define WS_RH     10005824          // 8192000 f: relu_h (if ws_size permits)

// ---------------------------------------------------------------- prep ----
__global__ __launch_bounds__(256) void prep(const float* __restrict__ ew_in,
                                            const float* __restrict__ ni,
                                            float* __restrict__ ws,
                                            float* __restrict__ out) {
    int i = blockIdx.x * 256 + threadIdx.x;       // grid covers 8192
    if (i < N_EDGES_C) {
        float w = ew_in[i];
        float s = (w < 0.2f) ? 0.0f : fminf(w, 1.0f);
        ws[WS_EWS + i] = s;
        out[128 + i] = s;                         // output 1: ew
    }
    if (i < N_NODES_C) {
        float v = ni[i];
        out[128 + N_EDGES_C + i] = fminf(fmaxf(v, 0.0f), 1.0f);  // output 2
    }
}

// ------------------------------- packed degree+count: 1 atomic per edge ---
__global__ __launch_bounds__(256) void deg_cnt(const int* __restrict__ ei,
                                               float* __restrict__ ws) {
    int e = blockIdx.x * 256 + threadIdx.x;       // < ET
    int d = ei[ET + e];
    float w = ws[WS_EWS + e % N_EDGES_C];
    unsigned long long pk =
        (1ull << 32) | (unsigned)(w * 65536.0f + 0.5f);
    atomicAdd((unsigned long long*)(ws + WS_PCK) + d, pk);
}

// --------------------------- per-graph: decode pck -> dinv, scan -> rowp --
__global__ __launch_bounds__(256) void csr_scan(float* __restrict__ ws) {
    __shared__ int cntl[N_NODES_C];
    __shared__ int rs[N_NODES_C + 8];
    __shared__ int wtot[4];
    int g = blockIdx.x, tid = threadIdx.x;
    int lane = tid & 63, wid = tid >> 6;
    int gbase = g * N_NODES_C;
    const unsigned long long* pck =
        (const unsigned long long*)(ws + WS_PCK) + gbase;

    for (int i = tid; i < N_NODES_C; i += 256) {
        unsigned long long p = pck[i];
        cntl[i] = (int)(p >> 32);
        float deg = 1.0f + (float)(unsigned)p * (1.0f / 65536.0f);  // +self loop
        ws[WS_DEG + gbase + i] = rsqrtf(deg);
    }
    __syncthreads();

    int s0 = 0, s1 = 0, s2 = 0, s3 = 0, tsum = 0;
    if (tid < 250) {
        s0 = cntl[4 * tid]; s1 = cntl[4 * tid + 1];
        s2 = cntl[4 * tid + 2]; s3 = cntl[4 * tid + 3];
        tsum = s0 + s1 + s2 + s3;
    }
    int v = tsum;
    #pragma unroll
    for (int off = 1; off < 64; off <<= 1) {
        int n = __shfl_up(v, off, 64);
        if (lane >= off) v += n;
    }
    if (lane == 63) wtot[wid] = v;
    __syncthreads();
    int base = 0;
    for (int w = 0; w < wid; ++w) base += wtot[w];
    int excl = base + v - tsum;
    if (tid < 250) {
        rs[4 * tid]     = excl;
        rs[4 * tid + 1] = excl + s0;
        rs[4 * tid + 2] = excl + s0 + s1;
        rs[4 * tid + 3] = excl + s0 + s1 + s2;
    }
    if (tid == 255) rs[N_NODES_C] = N_EDGES_C;
    __syncthreads();

    int* rowp = (int*)(ws + WS_ROWP) + g * 1024;
    int* cur  = (int*)(ws + WS_PCK) + gbase;      // alias: pck dead after decode
    for (int i = tid; i <= N_NODES_C; i += 256) rowp[i] = rs[i];
    for (int i = tid; i < N_NODES_C; i += 256) cur[i] = rs[i];
}

// ------------------------------------- scatter (src, norm) into CSR order -
__global__ __launch_bounds__(256) void scatter(const int* __restrict__ ei,
                                               float* __restrict__ ws) {
    int e = blockIdx.x * 256 + threadIdx.x;       // < ET
    int g = e / N_EDGES_C;
    int le = e - g * N_EDGES_C;
    int s = ei[e];
    int d = ei[ET + e];
    const float* dinv = ws + WS_DEG;
    float nm = dinv[s] * ws[WS_EWS + le] * dinv[d];
    int pos = atomicAdd((int*)(ws + WS_PCK) + d, 1);
    ((int2*)(ws + WS_PEDGE))[g * N_EDGES_C + pos] =
        make_int2(s, __float_as_int(nm));
}

// ------------------------------------------------------- h2 = (x*ni) @ W1 -
__global__ __launch_bounds__(256) void gemm_h2(const float* __restrict__ x,
                                               const float* __restrict__ ni,
                                               const float* __restrict__ W1,
                                               float* __restrict__ h2) {
    __shared__ float xs[128][65];
    __shared__ float wsm[64 * 128];
    int tid = threadIdx.x;
    int base = blockIdx.x * 128;

    #pragma unroll
    for (int i = 0; i < 8; ++i) {
        int idx = i * 1024 + tid * 4;
        int r = idx >> 6, d = idx & 63;
        float4 v = *(const float4*)&x[(base + r) * 64 + d];
        float s = ni[(base + r) % N_NODES_C];
        xs[r][d + 0] = v.x * s;
        xs[r][d + 1] = v.y * s;
        xs[r][d + 2] = v.z * s;
        xs[r][d + 3] = v.w * s;
    }
    #pragma unroll
    for (int i = 0; i < 8; ++i) {
        int idx = i * 1024 + tid * 4;
        *(float4*)&wsm[idx] = *(const float4*)&W1[idx];
    }
    __syncthreads();

    int tx = tid & 15, ty = tid >> 4;
    int r0 = ty * 8, c0 = tx * 8;
    float acc[8][8];
    #pragma unroll
    for (int i = 0; i < 8; ++i)
        #pragma unroll
        for (int j = 0; j < 8; ++j) acc[i][j] = 0.0f;

    for (int d = 0; d < 64; ++d) {
        float a[8];
        #pragma unroll
        for (int i = 0; i < 8; ++i) a[i] = xs[r0 + i][d];
        float4 b0 = *(float4*)&wsm[d * 128 + c0];
        float4 b1 = *(float4*)&wsm[d * 128 + c0 + 4];
        float b[8] = {b0.x, b0.y, b0.z, b0.w, b1.x, b1.y, b1.z, b1.w};
        #pragma unroll
        for (int i = 0; i < 8; ++i)
            #pragma unroll
            for (int j = 0; j < 8; ++j)
                acc[i][j] = fmaf(a[i], b[j], acc[i][j]);
    }

    #pragma unroll
    for (int i = 0; i < 8; ++i) {
        float* dst = &h2[(base + r0 + i) * HID_C + c0];
        float4 o0 = {acc[i][0], acc[i][1], acc[i][2], acc[i][3]};
        float4 o1 = {acc[i][4], acc[i][5], acc[i][6], acc[i][7]};
        *(float4*)dst = o0;
        *(float4*)(dst + 4) = o1;
    }
}

// ------------------------------------------- SpMM out-of-place (primary) --
__global__ __launch_bounds__(256) void spmm_op(const float* __restrict__ ws_ro,
                                               const float* __restrict__ h2,
                                               const float* __restrict__ b1,
                                               float* __restrict__ rh) {
    int bid = blockIdx.x;
    int g = bid & 63, slice = bid >> 6;            // slice < 32
    int t = threadIdx.x;
    if (t >= 250) return;
    int p = slice * 250 + t;                       // < 8000
    int dst = p >> 3, chunk = p & 7, c0 = chunk << 4;

    const int*  rowp  = (const int*)(ws_ro + WS_ROWP) + g * 1024;
    const int2* pedge = (const int2*)(ws_ro + WS_PEDGE) + g * N_EDGES_C;
    const float* dinv = ws_ro + WS_DEG;

    int e0 = rowp[dst], e1 = rowp[dst + 1];
    float4 a0 = {0,0,0,0}, a1 = {0,0,0,0}, a2 = {0,0,0,0}, a3 = {0,0,0,0};
    for (int e = e0; e < e1; ++e) {
        int2 ed = pedge[e];
        float nm = __int_as_float(ed.y);
        const float* hp = &h2[ed.x * HID_C + c0];
        float4 h0 = *(const float4*)(hp + 0);
        float4 h1 = *(const float4*)(hp + 4);
        float4 h2v = *(const float4*)(hp + 8);
        float4 h3 = *(const float4*)(hp + 12);
        a0.x = fmaf(h0.x, nm, a0.x); a0.y = fmaf(h0.y, nm, a0.y);
        a0.z = fmaf(h0.z, nm, a0.z); a0.w = fmaf(h0.w, nm, a0.w);
        a1.x = fmaf(h1.x, nm, a1.x); a1.y = fmaf(h1.y, nm, a1.y);
        a1.z = fmaf(h1.z, nm, a1.z); a1.w = fmaf(h1.w, nm, a1.w);
        a2.x = fmaf(h2v.x, nm, a2.x); a2.y = fmaf(h2v.y, nm, a2.y);
        a2.z = fmaf(h2v.z, nm, a2.z); a2.w = fmaf(h2v.w, nm, a2.w);
        a3.x = fmaf(h3.x, nm, a3.x); a3.y = fmaf(h3.y, nm, a3.y);
        a3.z = fmaf(h3.z, nm, a3.z); a3.w = fmaf(h3.w, nm, a3.w);
    }

    int node = g * N_NODES_C + dst;
    float dv = dinv[node], dv2 = dv * dv;
    const float* sp = &h2[node * HID_C + c0];
    float* op = &rh[node * HID_C + c0];
    #pragma unroll
    for (int q = 0; q < 4; ++q) {
        float4 sv = *(const float4*)(sp + q * 4);
        float4 bv = *(const float4*)&b1[c0 + q * 4];
        float4 av = q == 0 ? a0 : q == 1 ? a1 : q == 2 ? a2 : a3;
        float4 o;
        o.x = fmaxf(fmaf(sv.x, dv2, av.x) + bv.x, 0.0f);
        o.y = fmaxf(fmaf(sv.y, dv2, av.y) + bv.y, 0.0f);
        o.z = fmaxf(fmaf(sv.z, dv2, av.z) + bv.z, 0.0f);
        o.w = fmaxf(fmaf(sv.w, dv2, av.w) + bv.w, 0.0f);
        *(float4*)(op + q * 4) = o;
    }
}

// ------------------------- SpMM in-place fallback (small ws): 1024 thr ----
__global__ __launch_bounds__(1024) void spmm_ip(const float* __restrict__ ws_ro,
                                                float* __restrict__ h2,
                                                const float* __restrict__ b1) {
    __shared__ float res[N_NODES_C * 16];          // 64000 B
    int bid = blockIdx.x;
    int g  = bid & 63;
    int c0 = (bid >> 6) * 16;
    int tid = threadIdx.x;
    int fq = tid & 3, dslot = tid >> 2;            // 256 dsts in flight

    const int*  rowp  = (const int*)(ws_ro + WS_ROWP) + g * 1024;
    const int2* pedge = (const int2*)(ws_ro + WS_PEDGE) + g * N_EDGES_C;
    const float* dinv = ws_ro + WS_DEG;
    int gbase = g * N_NODES_C;

    for (int iter = 0; iter < 4; ++iter) {
        int d = iter * 256 + dslot;
        if (d < N_NODES_C) {
            int e0 = rowp[d], e1 = rowp[d + 1];
            float4 a = make_float4(0.f, 0.f, 0.f, 0.f);
            for (int e = e0; e < e1; ++e) {
                int2 ed = pedge[e];
                float nm = __int_as_float(ed.y);
                float4 hv = *(const float4*)&h2[ed.x * HID_C + c0 + fq * 4];
                a.x = fmaf(hv.x, nm, a.x);
                a.y = fmaf(hv.y, nm, a.y);
                a.z = fmaf(hv.z, nm, a.z);
                a.w = fmaf(hv.w, nm, a.w);
            }
            *(float4*)&res[d * 16 + fq * 4] = a;
        }
    }
    __syncthreads();

    for (int idx = tid; idx < N_NODES_C * 16; idx += 1024) {
        int v = idx >> 4, f = idx & 15;
        int node = gbase + v;
        float dv = dinv[node];
        float val = res[idx] + h2[node * HID_C + c0 + f] * (dv * dv) + b1[c0 + f];
        h2[node * HID_C + c0 + f] = fmaxf(val, 0.0f);
    }
}

// ------------------------------------------- g partials: rh @ Wn chunks ---
template<int CHUNK>
__global__ __launch_bounds__(256) void reduce_g(const float* __restrict__ rh,
                                                const float* __restrict__ Wn,
                                                float* __restrict__ part) {
    __shared__ float wn[CHUNK * 32];
    int tid = threadIdx.x;
    int k0 = blockIdx.x * CHUNK;
    for (int idx = tid * 4; idx < CHUNK * 32; idx += 1024)
        *(float4*)&wn[idx] = *(const float4*)&Wn[k0 * 32 + idx];
    __syncthreads();

    int j = tid & 31, bg = tid >> 5;               // bg: 8 graphs each
    float acc[8] = {0, 0, 0, 0, 0, 0, 0, 0};
    for (int kk = 0; kk < CHUNK; kk += 8) {
        float w[8];
        #pragma unroll
        for (int q = 0; q < 8; ++q) w[q] = wn[(kk + q) * 32 + j];
        #pragma unroll
        for (int u = 0; u < 8; ++u) {
            const float* rp = &rh[(bg * 8 + u) * 128000 + k0 + kk];
            float4 r0 = *(const float4*)(rp + 0);
            float4 r1 = *(const float4*)(rp + 4);
            acc[u] = fmaf(r0.x, w[0], acc[u]);
            acc[u] = fmaf(r0.y, w[1], acc[u]);
            acc[u] = fmaf(r0.z, w[2], acc[u]);
            acc[u] = fmaf(r0.w, w[3], acc[u]);
            acc[u] = fmaf(r1.x, w[4], acc[u]);
            acc[u] = fmaf(r1.y, w[5], acc[u]);
            acc[u] = fmaf(r1.z, w[6], acc[u]);
            acc[u] = fmaf(r1.w, w[7], acc[u]);
        }
    }
    #pragma unroll
    for (int u = 0; u < 8; ++u)
        part[blockIdx.x * 2048 + (bg * 8 + u) * 32 + j] = acc[u];
}

// -------------------- coalesced column-sum of part[nrows][2048] -> g2048 --
// 256 blocks; thread owns 8 consecutive cols; block strides rows. Every wave
// streams 2KB contiguous per row; one fp32 atomicAdd per (block, col).
__global__ __launch_bounds__(256) void sum_part(const float* __restrict__ part,
                                                float* __restrict__ g2048,
                                                int nrows) {
    int tid = threadIdx.x;
    int col0 = tid * 8;
    float4 a0 = {0,0,0,0}, a1 = {0,0,0,0};
    for (int r = blockIdx.x; r < nrows; r += 256) {
        const float* p = part + r * 2048 + col0;
        float4 v0 = *(const float4*)(p + 0);
        float4 v1 = *(const float4*)(p + 4);
        a0.x += v0.x; a0.y += v0.y; a0.z += v0.z; a0.w += v0.w;
        a1.x += v1.x; a1.y += v1.y; a1.z += v1.z; a1.w += v1.w;
    }
    atomicAdd(&g2048[col0 + 0], a0.x);
    atomicAdd(&g2048[col0 + 1], a0.y);
    atomicAdd(&g2048[col0 + 2], a0.z);
    atomicAdd(&g2048[col0 + 3], a0.w);
    atomicAdd(&g2048[col0 + 4], a1.x);
    atomicAdd(&g2048[col0 + 5], a1.y);
    atomicAdd(&g2048[col0 + 6], a1.z);
    atomicAdd(&g2048[col0 + 7], a1.w);
}

// ---------------------- final: g2048 + bn, @Wc, +bc (tiny) ----------------
__global__ void final_out(const float* __restrict__ g2048,
                          const float* __restrict__ bn,
                          const float* __restrict__ Wc,
                          const float* __restrict__ bc,
                          float* __restrict__ out) {
    int g = blockIdx.x;
    int j = threadIdx.x;                           // 64 threads, 32 active
    float o0 = 0.0f, o1 = 0.0f;
    if (j < 32) {
        float gv = g2048[g * 32 + j] + bn[j];
        o0 = gv * Wc[j * 2 + 0];
        o1 = gv * Wc[j * 2 + 1];
    }
    #pragma unroll
    for (int off = 32; off >= 1; off >>= 1) {
        o0 += __shfl_xor(o0, off);
        o1 += __shfl_xor(o1, off);
    }
    if (j == 0) {
        out[g * 2 + 0] = o0 + bc[0];
        out[g * 2 + 1] = o1 + bc[1];
    }
}

// --------------------------------------------------------------------------
extern "C" void kernel_launch(void* const* d_in, const int* in_sizes, int n_in,
                              void* d_out, int out_size, void* d_ws, size_t ws_size,
                              hipStream_t stream) {
    const float* x  = (const float*)d_in[0];
    const int*   ei = (const int*)d_in[1];
    const float* ew = (const float*)d_in[3];
    const float* ni = (const float*)d_in[4];
    const float* W1 = (const float*)d_in[5];
    const float* b1 = (const float*)d_in[6];
    const float* Wn = (const float*)d_in[7];
    const float* bn = (const float*)d_in[8];
    const float* Wc = (const float*)d_in[9];
    const float* bc = (const float*)d_in[10];
    float* out = (float*)d_out;
    float* ws  = (float*)d_ws;

    bool big = ws_size >= (size_t)(WS_RH + 8192000) * sizeof(float);
    float* h2 = ws + WS_H2;
    float* rh = big ? ws + WS_RH : h2;

    hipMemsetAsync(ws + WS_PCK, 0, 64000 * sizeof(unsigned long long), stream);
    prep<<<32, 256, 0, stream>>>(ew, ni, ws, out);
    gemm_h2<<<NT / 128, 256, 0, stream>>>(x, ni, W1, h2);
    deg_cnt<<<ET / 256, 256, 0, stream>>>(ei, ws);
    csr_scan<<<BATCH_C, 256, 0, stream>>>(ws);
    scatter<<<ET / 256, 256, 0, stream>>>(ei, ws);
    // EWS dead now -> g2048 lives there; zero it (8 KB, stream-ordered)
    hipMemsetAsync(ws + WS_G2048, 0, 2048 * sizeof(float), stream);
    if (big) {
        spmm_op<<<BATCH_C * 32, 256, 0, stream>>>(ws, h2, b1, rh);
        // h2 dead now -> its region holds reduce_g partials (1600*2048 f)
        reduce_g<80><<<1600, 256, 0, stream>>>(rh, Wn, ws + WS_H2);
        sum_part<<<256, 256, 0, stream>>>(ws + WS_H2, ws + WS_G2048, 1600);
    } else {
        spmm_ip<<<BATCH_C * 8, 1024, 0, stream>>>(ws, h2, b1);
        reduce_g<160><<<800, 256, 0, stream>>>(rh, Wn, ws + WS_PART2);
        sum_part<<<256, 256, 0, stream>>>(ws + WS_PART2, ws + WS_G2048, 800);
    }
    final_out<<<BATCH_C, 64, 0, stream>>>(ws + WS_G2048, bn, Wc, bc, out);
}

// Round 11
// 253.652 us; speedup vs baseline: 1.1686x; 1.1686x over previous
//
#include <hip/hip_runtime.h>

#define N_NODES_C 1000
#define N_EDGES_C 8000
#define BATCH_C   64
#define IN_DIM_C  64
#define HID_C     128
#define NT (BATCH_C * N_NODES_C)   // 64000 total nodes
#define ET (BATCH_C * N_EDGES_C)   // 512000 total edges

// workspace layout (float offsets)
#define WS_DEG    0                 // 64000 f: dinv (written by csr_scan)
#define WS_EWS    64000             // 8000 f: ews; dead after scatter ->
#define WS_G2048  64000             //   g2048 (2048 f) lives here afterwards
#define WS_PCK    72000             // 64000 u64: packed cnt<<32|deg -> cursors
#define WS_ROWP   200000            // 64*1024 i: per-graph CSR row starts
#define WS_PEDGE  265536            // 512000 int2: (src_global, norm) CSR order
#define WS_PART2S 72000             // small-ws path partials (dead CSR region)
#define WS_P2     72000             // big path: part2[256][2048] (dead CSR)
#define WS_H2     1813824           // 8192000 f: h2 (dead after spmm ->
                                    //   big-path reduce_g partials)
#define WS_RH     10005824          // 8192000 f: relu_h (if ws_size permits)

// ---------------------------------------------------------------- prep ----
__global__ __launch_bounds__(256) void prep(const float* __restrict__ ew_in,
                                            const float* __restrict__ ni,
                                            float* __restrict__ ws,
                                            float* __restrict__ out) {
    int i = blockIdx.x * 256 + threadIdx.x;       // grid covers 8192
    if (i < N_EDGES_C) {
        float w = ew_in[i];
        float s = (w < 0.2f) ? 0.0f : fminf(w, 1.0f);
        ws[WS_EWS + i] = s;
        out[128 + i] = s;                         // output 1: ew
    }
    if (i < N_NODES_C) {
        float v = ni[i];
        out[128 + N_EDGES_C + i] = fminf(fmaxf(v, 0.0f), 1.0f);  // output 2
    }
}

// ------------------------------- packed degree+count: 1 atomic per edge ---
__global__ __launch_bounds__(256) void deg_cnt(const int* __restrict__ ei,
                                               float* __restrict__ ws) {
    int e = blockIdx.x * 256 + threadIdx.x;       // < ET
    int d = ei[ET + e];
    float w = ws[WS_EWS + e % N_EDGES_C];
    unsigned long long pk =
        (1ull << 32) | (unsigned)(w * 65536.0f + 0.5f);
    atomicAdd((unsigned long long*)(ws + WS_PCK) + d, pk);
}

// --------------------------- per-graph: decode pck -> dinv, scan -> rowp --
__global__ __launch_bounds__(256) void csr_scan(float* __restrict__ ws) {
    __shared__ int cntl[N_NODES_C];
    __shared__ int rs[N_NODES_C + 8];
    __shared__ int wtot[4];
    int g = blockIdx.x, tid = threadIdx.x;
    int lane = tid & 63, wid = tid >> 6;
    int gbase = g * N_NODES_C;
    const unsigned long long* pck =
        (const unsigned long long*)(ws + WS_PCK) + gbase;

    for (int i = tid; i < N_NODES_C; i += 256) {
        unsigned long long p = pck[i];
        cntl[i] = (int)(p >> 32);
        float deg = 1.0f + (float)(unsigned)p * (1.0f / 65536.0f);  // +self loop
        ws[WS_DEG + gbase + i] = rsqrtf(deg);
    }
    __syncthreads();

    int s0 = 0, s1 = 0, s2 = 0, s3 = 0, tsum = 0;
    if (tid < 250) {
        s0 = cntl[4 * tid]; s1 = cntl[4 * tid + 1];
        s2 = cntl[4 * tid + 2]; s3 = cntl[4 * tid + 3];
        tsum = s0 + s1 + s2 + s3;
    }
    int v = tsum;
    #pragma unroll
    for (int off = 1; off < 64; off <<= 1) {
        int n = __shfl_up(v, off, 64);
        if (lane >= off) v += n;
    }
    if (lane == 63) wtot[wid] = v;
    __syncthreads();
    int base = 0;
    for (int w = 0; w < wid; ++w) base += wtot[w];
    int excl = base + v - tsum;
    if (tid < 250) {
        rs[4 * tid]     = excl;
        rs[4 * tid + 1] = excl + s0;
        rs[4 * tid + 2] = excl + s0 + s1;
        rs[4 * tid + 3] = excl + s0 + s1 + s2;
    }
    if (tid == 255) rs[N_NODES_C] = N_EDGES_C;
    __syncthreads();

    int* rowp = (int*)(ws + WS_ROWP) + g * 1024;
    int* cur  = (int*)(ws + WS_PCK) + gbase;      // alias: pck dead after decode
    for (int i = tid; i <= N_NODES_C; i += 256) rowp[i] = rs[i];
    for (int i = tid; i < N_NODES_C; i += 256) cur[i] = rs[i];
}

// ------------------------------------- scatter (src, norm) into CSR order -
__global__ __launch_bounds__(256) void scatter(const int* __restrict__ ei,
                                               float* __restrict__ ws) {
    int e = blockIdx.x * 256 + threadIdx.x;       // < ET
    int g = e / N_EDGES_C;
    int le = e - g * N_EDGES_C;
    int s = ei[e];
    int d = ei[ET + e];
    const float* dinv = ws + WS_DEG;
    float nm = dinv[s] * ws[WS_EWS + le] * dinv[d];
    int pos = atomicAdd((int*)(ws + WS_PCK) + d, 1);
    ((int2*)(ws + WS_PEDGE))[g * N_EDGES_C + pos] =
        make_int2(s, __float_as_int(nm));
}

// ------------------------------------------------------- h2 = (x*ni) @ W1 -
__global__ __launch_bounds__(256) void gemm_h2(const float* __restrict__ x,
                                               const float* __restrict__ ni,
                                               const float* __restrict__ W1,
                                               float* __restrict__ h2) {
    __shared__ float xs[128][65];
    __shared__ float wsm[64 * 128];
    int tid = threadIdx.x;
    int base = blockIdx.x * 128;

    #pragma unroll
    for (int i = 0; i < 8; ++i) {
        int idx = i * 1024 + tid * 4;
        int r = idx >> 6, d = idx & 63;
        float4 v = *(const float4*)&x[(base + r) * 64 + d];
        float s = ni[(base + r) % N_NODES_C];
        xs[r][d + 0] = v.x * s;
        xs[r][d + 1] = v.y * s;
        xs[r][d + 2] = v.z * s;
        xs[r][d + 3] = v.w * s;
    }
    #pragma unroll
    for (int i = 0; i < 8; ++i) {
        int idx = i * 1024 + tid * 4;
        *(float4*)&wsm[idx] = *(const float4*)&W1[idx];
    }
    __syncthreads();

    int tx = tid & 15, ty = tid >> 4;
    int r0 = ty * 8, c0 = tx * 8;
    float acc[8][8];
    #pragma unroll
    for (int i = 0; i < 8; ++i)
        #pragma unroll
        for (int j = 0; j < 8; ++j) acc[i][j] = 0.0f;

    for (int d = 0; d < 64; ++d) {
        float a[8];
        #pragma unroll
        for (int i = 0; i < 8; ++i) a[i] = xs[r0 + i][d];
        float4 b0 = *(float4*)&wsm[d * 128 + c0];
        float4 b1 = *(float4*)&wsm[d * 128 + c0 + 4];
        float b[8] = {b0.x, b0.y, b0.z, b0.w, b1.x, b1.y, b1.z, b1.w};
        #pragma unroll
        for (int i = 0; i < 8; ++i)
            #pragma unroll
            for (int j = 0; j < 8; ++j)
                acc[i][j] = fmaf(a[i], b[j], acc[i][j]);
    }

    #pragma unroll
    for (int i = 0; i < 8; ++i) {
        float* dst = &h2[(base + r0 + i) * HID_C + c0];
        float4 o0 = {acc[i][0], acc[i][1], acc[i][2], acc[i][3]};
        float4 o1 = {acc[i][4], acc[i][5], acc[i][6], acc[i][7]};
        *(float4*)dst = o0;
        *(float4*)(dst + 4) = o1;
    }
}

// ------------------------------------------- SpMM out-of-place (primary) --
__global__ __launch_bounds__(256) void spmm_op(const float* __restrict__ ws_ro,
                                               const float* __restrict__ h2,
                                               const float* __restrict__ b1,
                                               float* __restrict__ rh) {
    int bid = blockIdx.x;
    int g = bid & 63, slice = bid >> 6;            // slice < 32
    int t = threadIdx.x;
    if (t >= 250) return;
    int p = slice * 250 + t;                       // < 8000
    int dst = p >> 3, chunk = p & 7, c0 = chunk << 4;

    const int*  rowp  = (const int*)(ws_ro + WS_ROWP) + g * 1024;
    const int2* pedge = (const int2*)(ws_ro + WS_PEDGE) + g * N_EDGES_C;
    const float* dinv = ws_ro + WS_DEG;

    int e0 = rowp[dst], e1 = rowp[dst + 1];
    float4 a0 = {0,0,0,0}, a1 = {0,0,0,0}, a2 = {0,0,0,0}, a3 = {0,0,0,0};
    for (int e = e0; e < e1; ++e) {
        int2 ed = pedge[e];
        float nm = __int_as_float(ed.y);
        const float* hp = &h2[ed.x * HID_C + c0];
        float4 h0 = *(const float4*)(hp + 0);
        float4 h1 = *(const float4*)(hp + 4);
        float4 h2v = *(const float4*)(hp + 8);
        float4 h3 = *(const float4*)(hp + 12);
        a0.x = fmaf(h0.x, nm, a0.x); a0.y = fmaf(h0.y, nm, a0.y);
        a0.z = fmaf(h0.z, nm, a0.z); a0.w = fmaf(h0.w, nm, a0.w);
        a1.x = fmaf(h1.x, nm, a1.x); a1.y = fmaf(h1.y, nm, a1.y);
        a1.z = fmaf(h1.z, nm, a1.z); a1.w = fmaf(h1.w, nm, a1.w);
        a2.x = fmaf(h2v.x, nm, a2.x); a2.y = fmaf(h2v.y, nm, a2.y);
        a2.z = fmaf(h2v.z, nm, a2.z); a2.w = fmaf(h2v.w, nm, a2.w);
        a3.x = fmaf(h3.x, nm, a3.x); a3.y = fmaf(h3.y, nm, a3.y);
        a3.z = fmaf(h3.z, nm, a3.z); a3.w = fmaf(h3.w, nm, a3.w);
    }

    int node = g * N_NODES_C + dst;
    float dv = dinv[node], dv2 = dv * dv;
    const float* sp = &h2[node * HID_C + c0];
    float* op = &rh[node * HID_C + c0];
    #pragma unroll
    for (int q = 0; q < 4; ++q) {
        float4 sv = *(const float4*)(sp + q * 4);
        float4 bv = *(const float4*)&b1[c0 + q * 4];
        float4 av = q == 0 ? a0 : q == 1 ? a1 : q == 2 ? a2 : a3;
        float4 o;
        o.x = fmaxf(fmaf(sv.x, dv2, av.x) + bv.x, 0.0f);
        o.y = fmaxf(fmaf(sv.y, dv2, av.y) + bv.y, 0.0f);
        o.z = fmaxf(fmaf(sv.z, dv2, av.z) + bv.z, 0.0f);
        o.w = fmaxf(fmaf(sv.w, dv2, av.w) + bv.w, 0.0f);
        *(float4*)(op + q * 4) = o;
    }
}

// ------------------------- SpMM in-place fallback (small ws): 1024 thr ----
__global__ __launch_bounds__(1024) void spmm_ip(const float* __restrict__ ws_ro,
                                                float* __restrict__ h2,
                                                const float* __restrict__ b1) {
    __shared__ float res[N_NODES_C * 16];          // 64000 B
    int bid = blockIdx.x;
    int g  = bid & 63;
    int c0 = (bid >> 6) * 16;
    int tid = threadIdx.x;
    int fq = tid & 3, dslot = tid >> 2;            // 256 dsts in flight

    const int*  rowp  = (const int*)(ws_ro + WS_ROWP) + g * 1024;
    const int2* pedge = (const int2*)(ws_ro + WS_PEDGE) + g * N_EDGES_C;
    const float* dinv = ws_ro + WS_DEG;
    int gbase = g * N_NODES_C;

    for (int iter = 0; iter < 4; ++iter) {
        int d = iter * 256 + dslot;
        if (d < N_NODES_C) {
            int e0 = rowp[d], e1 = rowp[d + 1];
            float4 a = make_float4(0.f, 0.f, 0.f, 0.f);
            for (int e = e0; e < e1; ++e) {
                int2 ed = pedge[e];
                float nm = __int_as_float(ed.y);
                float4 hv = *(const float4*)&h2[ed.x * HID_C + c0 + fq * 4];
                a.x = fmaf(hv.x, nm, a.x);
                a.y = fmaf(hv.y, nm, a.y);
                a.z = fmaf(hv.z, nm, a.z);
                a.w = fmaf(hv.w, nm, a.w);
            }
            *(float4*)&res[d * 16 + fq * 4] = a;
        }
    }
    __syncthreads();

    for (int idx = tid; idx < N_NODES_C * 16; idx += 1024) {
        int v = idx >> 4, f = idx & 15;
        int node = gbase + v;
        float dv = dinv[node];
        float val = res[idx] + h2[node * HID_C + c0 + f] * (dv * dv) + b1[c0 + f];
        h2[node * HID_C + c0 + f] = fmaxf(val, 0.0f);
    }
}

// ------------------------------------------- g partials: rh @ Wn chunks ---
template<int CHUNK>
__global__ __launch_bounds__(256) void reduce_g(const float* __restrict__ rh,
                                                const float* __restrict__ Wn,
                                                float* __restrict__ part) {
    __shared__ float wn[CHUNK * 32];
    int tid = threadIdx.x;
    int k0 = blockIdx.x * CHUNK;
    for (int idx = tid * 4; idx < CHUNK * 32; idx += 1024)
        *(float4*)&wn[idx] = *(const float4*)&Wn[k0 * 32 + idx];
    __syncthreads();

    int j = tid & 31, bg = tid >> 5;               // bg: 8 graphs each
    float acc[8] = {0, 0, 0, 0, 0, 0, 0, 0};
    for (int kk = 0; kk < CHUNK; kk += 8) {
        float w[8];
        #pragma unroll
        for (int q = 0; q < 8; ++q) w[q] = wn[(kk + q) * 32 + j];
        #pragma unroll
        for (int u = 0; u < 8; ++u) {
            const float* rp = &rh[(bg * 8 + u) * 128000 + k0 + kk];
            float4 r0 = *(const float4*)(rp + 0);
            float4 r1 = *(const float4*)(rp + 4);
            acc[u] = fmaf(r0.x, w[0], acc[u]);
            acc[u] = fmaf(r0.y, w[1], acc[u]);
            acc[u] = fmaf(r0.z, w[2], acc[u]);
            acc[u] = fmaf(r0.w, w[3], acc[u]);
            acc[u] = fmaf(r1.x, w[4], acc[u]);
            acc[u] = fmaf(r1.y, w[5], acc[u]);
            acc[u] = fmaf(r1.z, w[6], acc[u]);
            acc[u] = fmaf(r1.w, w[7], acc[u]);
        }
    }
    #pragma unroll
    for (int u = 0; u < 8; ++u)
        part[blockIdx.x * 2048 + (bg * 8 + u) * 32 + j] = acc[u];
}

// ------------- stage 1: column partial-sum, NO atomics (coalesced) --------
// 256 blocks; thread owns 8 consecutive cols; block strides rows; each block
// writes ONE partial row to part2[bid][2048] (plain coalesced store).
__global__ __launch_bounds__(256) void sum_part_nc(const float* __restrict__ part,
                                                   float* __restrict__ part2,
                                                   int nrows) {
    int tid = threadIdx.x;
    int col0 = tid * 8;
    float4 a0 = {0,0,0,0}, a1 = {0,0,0,0};
    for (int r = blockIdx.x; r < nrows; r += 256) {
        const float* p = part + r * 2048 + col0;
        float4 v0 = *(const float4*)(p + 0);
        float4 v1 = *(const float4*)(p + 4);
        a0.x += v0.x; a0.y += v0.y; a0.z += v0.z; a0.w += v0.w;
        a1.x += v1.x; a1.y += v1.y; a1.z += v1.z; a1.w += v1.w;
    }
    float* q = part2 + blockIdx.x * 2048 + col0;
    *(float4*)(q + 0) = a0;
    *(float4*)(q + 4) = a1;
}

// ------------- stage 2: reduce src[nrows][2048] -> g2048, no atomics ------
// 32 blocks x (4 row-lanes x 64 cols); per-row each lane reads 256B
// contiguous; LDS-reduce the 4 lanes; coalesced 256B write per block.
__global__ __launch_bounds__(256) void sum2(const float* __restrict__ src,
                                            float* __restrict__ g2048,
                                            int nrows) {
    __shared__ float red[256];
    int tid = threadIdx.x;
    int c = (blockIdx.x << 6) | (tid & 63);
    int rl = tid >> 6;                             // 4 row-lanes
    float s = 0.0f;
    for (int r = rl; r < nrows; r += 4)
        s += src[r * 2048 + c];
    red[tid] = s;
    __syncthreads();
    if (tid < 64) {
        g2048[(blockIdx.x << 6) + tid] =
            red[tid] + red[tid + 64] + red[tid + 128] + red[tid + 192];
    }
}

// ---------------------- final: g2048 + bn, @Wc, +bc (tiny) ----------------
__global__ void final_out(const float* __restrict__ g2048,
                          const float* __restrict__ bn,
                          const float* __restrict__ Wc,
                          const float* __restrict__ bc,
                          float* __restrict__ out) {
    int g = blockIdx.x;
    int j = threadIdx.x;                           // 64 threads, 32 active
    float o0 = 0.0f, o1 = 0.0f;
    if (j < 32) {
        float gv = g2048[g * 32 + j] + bn[j];
        o0 = gv * Wc[j * 2 + 0];
        o1 = gv * Wc[j * 2 + 1];
    }
    #pragma unroll
    for (int off = 32; off >= 1; off >>= 1) {
        o0 += __shfl_xor(o0, off);
        o1 += __shfl_xor(o1, off);
    }
    if (j == 0) {
        out[g * 2 + 0] = o0 + bc[0];
        out[g * 2 + 1] = o1 + bc[1];
    }
}

// --------------------------------------------------------------------------
extern "C" void kernel_launch(void* const* d_in, const int* in_sizes, int n_in,
                              void* d_out, int out_size, void* d_ws, size_t ws_size,
                              hipStream_t stream) {
    const float* x  = (const float*)d_in[0];
    const int*   ei = (const int*)d_in[1];
    const float* ew = (const float*)d_in[3];
    const float* ni = (const float*)d_in[4];
    const float* W1 = (const float*)d_in[5];
    const float* b1 = (const float*)d_in[6];
    const float* Wn = (const float*)d_in[7];
    const float* bn = (const float*)d_in[8];
    const float* Wc = (const float*)d_in[9];
    const float* bc = (const float*)d_in[10];
    float* out = (float*)d_out;
    float* ws  = (float*)d_ws;

    bool big = ws_size >= (size_t)(WS_RH + 8192000) * sizeof(float);
    float* h2 = ws + WS_H2;
    float* rh = big ? ws + WS_RH : h2;

    hipMemsetAsync(ws + WS_PCK, 0, 64000 * sizeof(unsigned long long), stream);
    prep<<<32, 256, 0, stream>>>(ew, ni, ws, out);
    gemm_h2<<<NT / 128, 256, 0, stream>>>(x, ni, W1, h2);
    deg_cnt<<<ET / 256, 256, 0, stream>>>(ei, ws);
    csr_scan<<<BATCH_C, 256, 0, stream>>>(ws);
    scatter<<<ET / 256, 256, 0, stream>>>(ei, ws);
    if (big) {
        spmm_op<<<BATCH_C * 32, 256, 0, stream>>>(ws, h2, b1, rh);
        // h2 dead now -> its region holds reduce_g partials (1600*2048 f);
        // CSR region dead -> part2[256][2048] at WS_P2, g2048 at WS_G2048.
        reduce_g<80><<<1600, 256, 0, stream>>>(rh, Wn, ws + WS_H2);
        sum_part_nc<<<256, 256, 0, stream>>>(ws + WS_H2, ws + WS_P2, 1600);
        sum2<<<32, 256, 0, stream>>>(ws + WS_P2, ws + WS_G2048, 256);
    } else {
        spmm_ip<<<BATCH_C * 8, 1024, 0, stream>>>(ws, h2, b1);
        reduce_g<160><<<800, 256, 0, stream>>>(rh, Wn, ws + WS_PART2S);
        // small path: reduce part[800][2048] directly (cols strided but short)
        sum2<<<32, 256, 0, stream>>>(ws + WS_PART2S, ws + WS_G2048, 800);
    }
    final_out<<<BATCH_C, 64, 0, stream>>>(ws + WS_G2048, bn, Wc, bc, out);
}

// Round 13
// 234.811 us; speedup vs baseline: 1.2624x; 1.0802x over previous
//
#include <hip/hip_runtime.h>

#define N_NODES_C 1000
#define N_EDGES_C 8000
#define BATCH_C   64
#define IN_DIM_C  64
#define HID_C     128
#define NT (BATCH_C * N_NODES_C)   // 64000 total nodes
#define ET (BATCH_C * N_EDGES_C)   // 512000 total edges

// workspace layout (float offsets)
#define WS_DEG    0                 // 64000 f: dinv (written by csr_scan)
#define WS_EWS    64000             // 8000 f: ews; dead after scatter ->
#define WS_G2048  64000             //   g2048 (2048 f) lives here afterwards
#define WS_PCK    72000             // 64000 u64: packed cnt<<32|deg -> cursors
#define WS_ROWP   200000            // 64*1024 i: per-graph CSR row starts
#define WS_PEDGE  265536            // 512000 int2: (src_global, norm) CSR order
#define WS_PART2S 72000             // small-ws path partials (dead CSR region)
#define WS_P2     72000             // big path: part2[256][2048] (dead CSR)
#define WS_H2     1813824           // 8192000 f: h2 (dead after spmm ->
                                    //   big-path reduce_g partials 2000*2048)
#define WS_RH     10005824          // 8192000 f: relu_h (if ws_size permits)

// ---------------------------------------------------------------- prep ----
__global__ __launch_bounds__(256) void prep(const float* __restrict__ ew_in,
                                            const float* __restrict__ ni,
                                            float* __restrict__ ws,
                                            float* __restrict__ out) {
    int i = blockIdx.x * 256 + threadIdx.x;       // grid covers 8192
    if (i < N_EDGES_C) {
        float w = ew_in[i];
        float s = (w < 0.2f) ? 0.0f : fminf(w, 1.0f);
        ws[WS_EWS + i] = s;
        out[128 + i] = s;                         // output 1: ew
    }
    if (i < N_NODES_C) {
        float v = ni[i];
        out[128 + N_EDGES_C + i] = fminf(fmaxf(v, 0.0f), 1.0f);  // output 2
    }
}

// ------------------------------- packed degree+count: 1 atomic per edge ---
__global__ __launch_bounds__(256) void deg_cnt(const int* __restrict__ ei,
                                               float* __restrict__ ws) {
    int e = blockIdx.x * 256 + threadIdx.x;       // < ET
    int d = ei[ET + e];
    float w = ws[WS_EWS + e % N_EDGES_C];
    unsigned long long pk =
        (1ull << 32) | (unsigned)(w * 65536.0f + 0.5f);
    atomicAdd((unsigned long long*)(ws + WS_PCK) + d, pk);
}

// --------------------------- per-graph: decode pck -> dinv, scan -> rowp --
__global__ __launch_bounds__(256) void csr_scan(float* __restrict__ ws) {
    __shared__ int cntl[N_NODES_C];
    __shared__ int rs[N_NODES_C + 8];
    __shared__ int wtot[4];
    int g = blockIdx.x, tid = threadIdx.x;
    int lane = tid & 63, wid = tid >> 6;
    int gbase = g * N_NODES_C;
    const unsigned long long* pck =
        (const unsigned long long*)(ws + WS_PCK) + gbase;

    for (int i = tid; i < N_NODES_C; i += 256) {
        unsigned long long p = pck[i];
        cntl[i] = (int)(p >> 32);
        float deg = 1.0f + (float)(unsigned)p * (1.0f / 65536.0f);  // +self loop
        ws[WS_DEG + gbase + i] = rsqrtf(deg);
    }
    __syncthreads();

    int s0 = 0, s1 = 0, s2 = 0, s3 = 0, tsum = 0;
    if (tid < 250) {
        s0 = cntl[4 * tid]; s1 = cntl[4 * tid + 1];
        s2 = cntl[4 * tid + 2]; s3 = cntl[4 * tid + 3];
        tsum = s0 + s1 + s2 + s3;
    }
    int v = tsum;
    #pragma unroll
    for (int off = 1; off < 64; off <<= 1) {
        int n = __shfl_up(v, off, 64);
        if (lane >= off) v += n;
    }
    if (lane == 63) wtot[wid] = v;
    __syncthreads();
    int base = 0;
    for (int w = 0; w < wid; ++w) base += wtot[w];
    int excl = base + v - tsum;
    if (tid < 250) {
        rs[4 * tid]     = excl;
        rs[4 * tid + 1] = excl + s0;
        rs[4 * tid + 2] = excl + s0 + s1;
        rs[4 * tid + 3] = excl + s0 + s1 + s2;
    }
    if (tid == 255) rs[N_NODES_C] = N_EDGES_C;
    __syncthreads();

    int* rowp = (int*)(ws + WS_ROWP) + g * 1024;
    int* cur  = (int*)(ws + WS_PCK) + gbase;      // alias: pck dead after decode
    for (int i = tid; i <= N_NODES_C; i += 256) rowp[i] = rs[i];
    for (int i = tid; i < N_NODES_C; i += 256) cur[i] = rs[i];
}

// ------------------------------------- scatter (src, norm) into CSR order -
__global__ __launch_bounds__(256) void scatter(const int* __restrict__ ei,
                                               float* __restrict__ ws) {
    int e = blockIdx.x * 256 + threadIdx.x;       // < ET
    int g = e / N_EDGES_C;
    int le = e - g * N_EDGES_C;
    int s = ei[e];
    int d = ei[ET + e];
    const float* dinv = ws + WS_DEG;
    float nm = dinv[s] * ws[WS_EWS + le] * dinv[d];
    int pos = atomicAdd((int*)(ws + WS_PCK) + d, 1);
    ((int2*)(ws + WS_PEDGE))[g * N_EDGES_C + pos] =
        make_int2(s, __float_as_int(nm));
}

// ------------------------------------------------------- h2 = (x*ni) @ W1 -
__global__ __launch_bounds__(256) void gemm_h2(const float* __restrict__ x,
                                               const float* __restrict__ ni,
                                               const float* __restrict__ W1,
                                               float* __restrict__ h2) {
    __shared__ float xs[128][65];
    __shared__ float wsm[64 * 128];
    int tid = threadIdx.x;
    int base = blockIdx.x * 128;

    #pragma unroll
    for (int i = 0; i < 8; ++i) {
        int idx = i * 1024 + tid * 4;
        int r = idx >> 6, d = idx & 63;
        float4 v = *(const float4*)&x[(base + r) * 64 + d];
        float s = ni[(base + r) % N_NODES_C];
        xs[r][d + 0] = v.x * s;
        xs[r][d + 1] = v.y * s;
        xs[r][d + 2] = v.z * s;
        xs[r][d + 3] = v.w * s;
    }
    #pragma unroll
    for (int i = 0; i < 8; ++i) {
        int idx = i * 1024 + tid * 4;
        *(float4*)&wsm[idx] = *(const float4*)&W1[idx];
    }
    __syncthreads();

    int tx = tid & 15, ty = tid >> 4;
    int r0 = ty * 8, c0 = tx * 8;
    float acc[8][8];
    #pragma unroll
    for (int i = 0; i < 8; ++i)
        #pragma unroll
        for (int j = 0; j < 8; ++j) acc[i][j] = 0.0f;

    for (int d = 0; d < 64; ++d) {
        float a[8];
        #pragma unroll
        for (int i = 0; i < 8; ++i) a[i] = xs[r0 + i][d];
        float4 b0 = *(float4*)&wsm[d * 128 + c0];
        float4 b1 = *(float4*)&wsm[d * 128 + c0 + 4];
        float b[8] = {b0.x, b0.y, b0.z, b0.w, b1.x, b1.y, b1.z, b1.w};
        #pragma unroll
        for (int i = 0; i < 8; ++i)
            #pragma unroll
            for (int j = 0; j < 8; ++j)
                acc[i][j] = fmaf(a[i], b[j], acc[i][j]);
    }

    #pragma unroll
    for (int i = 0; i < 8; ++i) {
        float* dst = &h2[(base + r0 + i) * HID_C + c0];
        float4 o0 = {acc[i][0], acc[i][1], acc[i][2], acc[i][3]};
        float4 o1 = {acc[i][4], acc[i][5], acc[i][6], acc[i][7]};
        *(float4*)dst = o0;
        *(float4*)(dst + 4) = o1;
    }
}

// ------------------------------------------- SpMM out-of-place (primary) --
__global__ __launch_bounds__(256) void spmm_op(const float* __restrict__ ws_ro,
                                               const float* __restrict__ h2,
                                               const float* __restrict__ b1,
                                               float* __restrict__ rh) {
    int bid = blockIdx.x;
    int g = bid & 63, slice = bid >> 6;            // slice < 32
    int t = threadIdx.x;
    if (t >= 250) return;
    int p = slice * 250 + t;                       // < 8000
    int dst = p >> 3, chunk = p & 7, c0 = chunk << 4;

    const int*  rowp  = (const int*)(ws_ro + WS_ROWP) + g * 1024;
    const int2* pedge = (const int2*)(ws_ro + WS_PEDGE) + g * N_EDGES_C;
    const float* dinv = ws_ro + WS_DEG;

    int e0 = rowp[dst], e1 = rowp[dst + 1];
    float4 a0 = {0,0,0,0}, a1 = {0,0,0,0}, a2 = {0,0,0,0}, a3 = {0,0,0,0};
    for (int e = e0; e < e1; ++e) {
        int2 ed = pedge[e];
        float nm = __int_as_float(ed.y);
        const float* hp = &h2[ed.x * HID_C + c0];
        float4 h0 = *(const float4*)(hp + 0);
        float4 h1 = *(const float4*)(hp + 4);
        float4 h2v = *(const float4*)(hp + 8);
        float4 h3 = *(const float4*)(hp + 12);
        a0.x = fmaf(h0.x, nm, a0.x); a0.y = fmaf(h0.y, nm, a0.y);
        a0.z = fmaf(h0.z, nm, a0.z); a0.w = fmaf(h0.w, nm, a0.w);
        a1.x = fmaf(h1.x, nm, a1.x); a1.y = fmaf(h1.y, nm, a1.y);
        a1.z = fmaf(h1.z, nm, a1.z); a1.w = fmaf(h1.w, nm, a1.w);
        a2.x = fmaf(h2v.x, nm, a2.x); a2.y = fmaf(h2v.y, nm, a2.y);
        a2.z = fmaf(h2v.z, nm, a2.z); a2.w = fmaf(h2v.w, nm, a2.w);
        a3.x = fmaf(h3.x, nm, a3.x); a3.y = fmaf(h3.y, nm, a3.y);
        a3.z = fmaf(h3.z, nm, a3.z); a3.w = fmaf(h3.w, nm, a3.w);
    }

    int node = g * N_NODES_C + dst;
    float dv = dinv[node], dv2 = dv * dv;
    const float* sp = &h2[node * HID_C + c0];
    float* op = &rh[node * HID_C + c0];
    #pragma unroll
    for (int q = 0; q < 4; ++q) {
        float4 sv = *(const float4*)(sp + q * 4);
        float4 bv = *(const float4*)&b1[c0 + q * 4];
        float4 av = q == 0 ? a0 : q == 1 ? a1 : q == 2 ? a2 : a3;
        float4 o;
        o.x = fmaxf(fmaf(sv.x, dv2, av.x) + bv.x, 0.0f);
        o.y = fmaxf(fmaf(sv.y, dv2, av.y) + bv.y, 0.0f);
        o.z = fmaxf(fmaf(sv.z, dv2, av.z) + bv.z, 0.0f);
        o.w = fmaxf(fmaf(sv.w, dv2, av.w) + bv.w, 0.0f);
        *(float4*)(op + q * 4) = o;
    }
}

// ------------------------- SpMM in-place fallback (small ws): 1024 thr ----
__global__ __launch_bounds__(1024) void spmm_ip(const float* __restrict__ ws_ro,
                                                float* __restrict__ h2,
                                                const float* __restrict__ b1) {
    __shared__ float res[N_NODES_C * 16];          // 64000 B
    int bid = blockIdx.x;
    int g  = bid & 63;
    int c0 = (bid >> 6) * 16;
    int tid = threadIdx.x;
    int fq = tid & 3, dslot = tid >> 2;            // 256 dsts in flight

    const int*  rowp  = (const int*)(ws_ro + WS_ROWP) + g * 1024;
    const int2* pedge = (const int2*)(ws_ro + WS_PEDGE) + g * N_EDGES_C;
    const float* dinv = ws_ro + WS_DEG;
    int gbase = g * N_NODES_C;

    for (int iter = 0; iter < 4; ++iter) {
        int d = iter * 256 + dslot;
        if (d < N_NODES_C) {
            int e0 = rowp[d], e1 = rowp[d + 1];
            float4 a = make_float4(0.f, 0.f, 0.f, 0.f);
            for (int e = e0; e < e1; ++e) {
                int2 ed = pedge[e];
                float nm = __int_as_float(ed.y);
                float4 hv = *(const float4*)&h2[ed.x * HID_C + c0 + fq * 4];
                a.x = fmaf(hv.x, nm, a.x);
                a.y = fmaf(hv.y, nm, a.y);
                a.z = fmaf(hv.z, nm, a.z);
                a.w = fmaf(hv.w, nm, a.w);
            }
            *(float4*)&res[d * 16 + fq * 4] = a;
        }
    }
    __syncthreads();

    for (int idx = tid; idx < N_NODES_C * 16; idx += 1024) {
        int v = idx >> 4, f = idx & 15;
        int node = gbase + v;
        float dv = dinv[node];
        float val = res[idx] + h2[node * HID_C + c0 + f] * (dv * dv) + b1[c0 + f];
        h2[node * HID_C + c0 + f] = fmaxf(val, 0.0f);
    }
}

// ---------------- g partials, LDS-staged (big path): rh @ Wn chunks -------
// CHUNK=64, 2000 blocks, 24KB LDS -> ~6 blocks/CU. Coalesced global loads
// stage rhs[64][64] + wn[64][32]; the j-per-lane dot product then reads LDS,
// where the 32-lane same-address rhs read is a FREE broadcast (the old
// version's global broadcast loads delivered only 32B/wave -> issue-bound).
__global__ __launch_bounds__(256) void reduce_g_stg(const float* __restrict__ rh,
                                                    const float* __restrict__ Wn,
                                                    float* __restrict__ part) {
    __shared__ float wn[64 * 32];                  // 8 KB
    __shared__ float rhs[64][64];                  // 16 KB
    int tid = threadIdx.x;
    int k0 = blockIdx.x * 64;

    // stage Wn slice (2048 floats, coalesced)
    #pragma unroll
    for (int idx = tid * 4; idx < 64 * 32; idx += 1024)
        *(float4*)&wn[idx] = *(const float4*)&Wn[k0 * 32 + idx];
    // stage rh: 64 rows x 64 k (4-lane clusters read 64B contiguous per row)
    {
        int row = tid >> 2, fq = tid & 3;
        const float* rp = &rh[row * 128000 + k0];
        #pragma unroll
        for (int q = 0; q < 4; ++q) {
            int col = q * 16 + fq * 4;
            *(float4*)&rhs[row][col] = *(const float4*)(rp + col);
        }
    }
    __syncthreads();

    int j = tid & 31, bg = tid >> 5;               // bg: 8 graphs each
    float acc[8] = {0, 0, 0, 0, 0, 0, 0, 0};
    for (int kk = 0; kk < 64; kk += 4) {
        float w0 = wn[(kk + 0) * 32 + j];
        float w1 = wn[(kk + 1) * 32 + j];
        float w2 = wn[(kk + 2) * 32 + j];
        float w3 = wn[(kk + 3) * 32 + j];
        #pragma unroll
        for (int u = 0; u < 8; ++u) {
            float4 r = *(const float4*)&rhs[bg * 8 + u][kk];  // LDS broadcast
            acc[u] = fmaf(r.x, w0, acc[u]);
            acc[u] = fmaf(r.y, w1, acc[u]);
            acc[u] = fmaf(r.z, w2, acc[u]);
            acc[u] = fmaf(r.w, w3, acc[u]);
        }
    }
    #pragma unroll
    for (int u = 0; u < 8; ++u)
        part[blockIdx.x * 2048 + (bg * 8 + u) * 32 + j] = acc[u];
}

// ---------------- g partials, non-staged (small-ws fallback) --------------
template<int CHUNK>
__global__ __launch_bounds__(256) void reduce_g(const float* __restrict__ rh,
                                                const float* __restrict__ Wn,
                                                float* __restrict__ part) {
    __shared__ float wn[CHUNK * 32];
    int tid = threadIdx.x;
    int k0 = blockIdx.x * CHUNK;
    for (int idx = tid * 4; idx < CHUNK * 32; idx += 1024)
        *(float4*)&wn[idx] = *(const float4*)&Wn[k0 * 32 + idx];
    __syncthreads();

    int j = tid & 31, bg = tid >> 5;
    float acc[8] = {0, 0, 0, 0, 0, 0, 0, 0};
    for (int kk = 0; kk < CHUNK; kk += 8) {
        float w[8];
        #pragma unroll
        for (int q = 0; q < 8; ++q) w[q] = wn[(kk + q) * 32 + j];
        #pragma unroll
        for (int u = 0; u < 8; ++u) {
            const float* rp = &rh[(bg * 8 + u) * 128000 + k0 + kk];
            float4 r0 = *(const float4*)(rp + 0);
            float4 r1 = *(const float4*)(rp + 4);
            acc[u] = fmaf(r0.x, w[0], acc[u]);
            acc[u] = fmaf(r0.y, w[1], acc[u]);
            acc[u] = fmaf(r0.z, w[2], acc[u]);
            acc[u] = fmaf(r0.w, w[3], acc[u]);
            acc[u] = fmaf(r1.x, w[4], acc[u]);
            acc[u] = fmaf(r1.y, w[5], acc[u]);
            acc[u] = fmaf(r1.z, w[6], acc[u]);
            acc[u] = fmaf(r1.w, w[7], acc[u]);
        }
    }
    #pragma unroll
    for (int u = 0; u < 8; ++u)
        part[blockIdx.x * 2048 + (bg * 8 + u) * 32 + j] = acc[u];
}

// ------------- stage 1: column partial-sum, NO atomics (coalesced) --------
__global__ __launch_bounds__(256) void sum_part_nc(const float* __restrict__ part,
                                                   float* __restrict__ part2,
                                                   int nrows) {
    int tid = threadIdx.x;
    int col0 = tid * 8;
    float4 a0 = {0,0,0,0}, a1 = {0,0,0,0};
    for (int r = blockIdx.x; r < nrows; r += 256) {
        const float* p = part + r * 2048 + col0;
        float4 v0 = *(const float4*)(p + 0);
        float4 v1 = *(const float4*)(p + 4);
        a0.x += v0.x; a0.y += v0.y; a0.z += v0.z; a0.w += v0.w;
        a1.x += v1.x; a1.y += v1.y; a1.z += v1.z; a1.w += v1.w;
    }
    float* q = part2 + blockIdx.x * 2048 + col0;
    *(float4*)(q + 0) = a0;
    *(float4*)(q + 4) = a1;
}

// ------------- stage 2: reduce src[nrows][2048] -> g2048, no atomics ------
__global__ __launch_bounds__(256) void sum2(const float* __restrict__ src,
                                            float* __restrict__ g2048,
                                            int nrows) {
    __shared__ float red[256];
    int tid = threadIdx.x;
    int c = (blockIdx.x << 6) | (tid & 63);
    int rl = tid >> 6;                             // 4 row-lanes
    float s = 0.0f;
    for (int r = rl; r < nrows; r += 4)
        s += src[r * 2048 + c];
    red[tid] = s;
    __syncthreads();
    if (tid < 64) {
        g2048[(blockIdx.x << 6) + tid] =
            red[tid] + red[tid + 64] + red[tid + 128] + red[tid + 192];
    }
}

// ---------------------- final: g2048 + bn, @Wc, +bc (tiny) ----------------
__global__ void final_out(const float* __restrict__ g2048,
                          const float* __restrict__ bn,
                          const float* __restrict__ Wc,
                          const float* __restrict__ bc,
                          float* __restrict__ out) {
    int g = blockIdx.x;
    int j = threadIdx.x;                           // 64 threads, 32 active
    float o0 = 0.0f, o1 = 0.0f;
    if (j < 32) {
        float gv = g2048[g * 32 + j] + bn[j];
        o0 = gv * Wc[j * 2 + 0];
        o1 = gv * Wc[j * 2 + 1];
    }
    #pragma unroll
    for (int off = 32; off >= 1; off >>= 1) {
        o0 += __shfl_xor(o0, off);
        o1 += __shfl_xor(o1, off);
    }
    if (j == 0) {
        out[g * 2 + 0] = o0 + bc[0];
        out[g * 2 + 1] = o1 + bc[1];
    }
}

// --------------------------------------------------------------------------
extern "C" void kernel_launch(void* const* d_in, const int* in_sizes, int n_in,
                              void* d_out, int out_size, void* d_ws, size_t ws_size,
                              hipStream_t stream) {
    const float* x  = (const float*)d_in[0];
    const int*   ei = (const int*)d_in[1];
    const float* ew = (const float*)d_in[3];
    const float* ni = (const float*)d_in[4];
    const float* W1 = (const float*)d_in[5];
    const float* b1 = (const float*)d_in[6];
    const float* Wn = (const float*)d_in[7];
    const float* bn = (const float*)d_in[8];
    const float* Wc = (const float*)d_in[9];
    const float* bc = (const float*)d_in[10];
    float* out = (float*)d_out;
    float* ws  = (float*)d_ws;

    bool big = ws_size >= (size_t)(WS_RH + 8192000) * sizeof(float);
    float* h2 = ws + WS_H2;
    float* rh = big ? ws + WS_RH : h2;

    hipMemsetAsync(ws + WS_PCK, 0, 64000 * sizeof(unsigned long long), stream);
    prep<<<32, 256, 0, stream>>>(ew, ni, ws, out);
    gemm_h2<<<NT / 128, 256, 0, stream>>>(x, ni, W1, h2);
    deg_cnt<<<ET / 256, 256, 0, stream>>>(ei, ws);
    csr_scan<<<BATCH_C, 256, 0, stream>>>(ws);
    scatter<<<ET / 256, 256, 0, stream>>>(ei, ws);
    if (big) {
        spmm_op<<<BATCH_C * 32, 256, 0, stream>>>(ws, h2, b1, rh);
        // h2 dead now -> its region holds reduce_g partials (2000*2048 f);
        // CSR region dead -> part2[256][2048] at WS_P2, g2048 at WS_G2048.
        reduce_g_stg<<<2000, 256, 0, stream>>>(rh, Wn, ws + WS_H2);
        sum_part_nc<<<256, 256, 0, stream>>>(ws + WS_H2, ws + WS_P2, 2000);
        sum2<<<32, 256, 0, stream>>>(ws + WS_P2, ws + WS_G2048, 256);
    } else {
        spmm_ip<<<BATCH_C * 8, 1024, 0, stream>>>(ws, h2, b1);
        reduce_g<160><<<800, 256, 0, stream>>>(rh, Wn, ws + WS_PART2S);
        sum2<<<32, 256, 0, stream>>>(ws + WS_PART2S, ws + WS_G2048, 800);
    }
    final_out<<<BATCH_C, 64, 0, stream>>>(ws + WS_G2048, bn, Wc, bc, out);
}